// Round 2
// baseline (247.907 us; speedup 1.0000x reference)
//
#include <hip/hip_runtime.h>

typedef unsigned short u16;
typedef unsigned int u32;
typedef unsigned long long u64;
typedef __attribute__((ext_vector_type(8))) short bfrag;  // 8 bf16 (4 VGPRs)
typedef __attribute__((ext_vector_type(4))) short sfrag;  // 4 bf16 (2 VGPRs)
typedef __attribute__((ext_vector_type(4))) float ffrag;  // 4 fp32

// B=256, L=200, D=256, H=16, Dh=16, M=51200
// Head-major slice: [B,H,L,16], slice stride 3200 u16, b-stride 51200 u16.

__device__ __forceinline__ float bf2f(u16 u) {
    union { float f; u32 i; } c; c.i = ((u32)u) << 16; return c.f;
}
__device__ __forceinline__ u16 f2bf(float f) {           // RNE
    union { float f; u32 i; } c; c.f = f;
    u32 r = c.i + 0x7FFFu + ((c.i >> 16) & 1u);
    return (u16)(r >> 16);
}
__device__ __forceinline__ u32 pack2bf(float lo, float hi) {  // RNE pair
    union { float f; u32 i; } a, b; a.f = lo; b.f = hi;
    u32 ra = a.i + 0x7FFFu + ((a.i >> 16) & 1u);
    u32 rb = b.i + 0x7FFFu + ((b.i >> 16) & 1u);
    return (ra >> 16) | (rb & 0xFFFF0000u);
}
__device__ __forceinline__ ffrag mfma16(bfrag a, bfrag b, ffrag c) {
    return __builtin_amdgcn_mfma_f32_16x16x32_bf16(a, b, c, 0, 0, 0);
}
__device__ __forceinline__ ffrag mfma16k16(sfrag a, sfrag b, ffrag c) {
    return __builtin_amdgcn_mfma_f32_16x16x16bf16_1k(a, b, c, 0, 0, 0);
}
// Async global->LDS, 16B per lane. LDS dest = wave-uniform base + lane*16.
__device__ __forceinline__ void gload16(const u16* g, u16* l) {
    __builtin_amdgcn_global_load_lds(
        (const __attribute__((address_space(1))) u32*)g,
        (__attribute__((address_space(3))) u32*)l, 16, 0, 0);
}

// ---------------------------------------------------------------------------
// LDS-tiled transpose+cast: W[k][n] f32 -> Wt[n][k] bf16, 4 matrices.
// ---------------------------------------------------------------------------
__global__ __launch_bounds__(256) void wtrans_k(
    const float* __restrict__ W0, const float* __restrict__ W1,
    const float* __restrict__ W2, const float* __restrict__ W3,
    u16* __restrict__ Wt)
{
    __shared__ u16 t_s[64][72];
    const int mat = blockIdx.z;
    const float* W = (mat == 0) ? W0 : (mat == 1) ? W1 : (mat == 2) ? W2 : W3;
    const int k0 = blockIdx.x * 64, n0 = blockIdx.y * 64;
    const int r = threadIdx.x >> 2, cq = threadIdx.x & 3;

    const float* src = W + (size_t)(k0 + r) * 256 + n0 + cq * 16;
#pragma unroll
    for (int j = 0; j < 16; j += 4) {
        float4 f = *(const float4*)(src + j);
        t_s[cq * 16 + j + 0][r] = f2bf(f.x);
        t_s[cq * 16 + j + 1][r] = f2bf(f.y);
        t_s[cq * 16 + j + 2][r] = f2bf(f.z);
        t_s[cq * 16 + j + 3][r] = f2bf(f.w);
    }
    __syncthreads();
    u16* dst = Wt + ((size_t)mat * 256 + n0 + r) * 256 + k0 + cq * 16;
    *(bfrag*)(dst)     = *(const bfrag*)&t_s[r][cq * 16];
    *(bfrag*)(dst + 8) = *(const bfrag*)&t_s[r][cq * 16 + 8];
}

// ---------------------------------------------------------------------------
// GEMM v3: tile 64x256, grid (800, nmat). 4 waves, wave tile 64x64, acc[4][4]
// (64 regs -> 3 waves/SIMD with __launch_bounds__(256,3)). Double-buffered
// LDS (40 KB), ONE barrier per K-step, issue-early/write-late staging (T14).
// B staged via global_load_lds width=16 (swizzle pre-applied to the per-lane
// GLOBAL source row, LDS dest linear). QKV A: f32 load + RNE pack (reg-staged,
// write-late). Proj A: global_load_lds from head-major bf16 ctx.
// ---------------------------------------------------------------------------
template<bool QKV>
__global__ __launch_bounds__(256, 3) void gemm_k(
    const void* __restrict__ Avp, const u16* __restrict__ Wtp,
    const float* __restrict__ b0, const float* __restrict__ b1,
    const float* __restrict__ b2,
    u16* __restrict__ o0, u16* __restrict__ o1, u16* __restrict__ o2)
{
    const int m0 = blockIdx.x * 64;
    const int matid = blockIdx.y;          // QKV: 0=Q 1=K 2=V; proj: 0
    const int tid = threadIdx.x;
    const int wave = tid >> 6, lane = tid & 63;
    const int quad = lane >> 4, l16 = lane & 15;

    __shared__ __align__(16) u16 a_s[2][4][64][8];    //  8 KB
    __shared__ __align__(16) u16 b_s[2][4][256][8];   // 32 KB

    ffrag zf = {0.f, 0.f, 0.f, 0.f};
    ffrag acc[4][4];
#pragma unroll
    for (int mi = 0; mi < 4; mi++)
#pragma unroll
        for (int ni = 0; ni < 4; ni++) acc[mi][ni] = zf;

    const int sr = tid >> 2;               // 0..63
    const int sc = tid & 3;                // 0..3 (k-octet)
    const float* Af = (const float*)Avp;
    const u16*   Ab = (const u16*)Avp;

    // ---- B source pointers: wave w owns LDS plane w. Slot row x holds
    // W row (x ^ (w<<2)); lane l covers slot p4*64+l.
    const u16* bp[4];
#pragma unroll
    for (int p4 = 0; p4 < 4; p4++) {
        int n = (p4 * 64 + lane) ^ (wave << 2);
        bp[p4] = Wtp + (size_t)(matid * 256 + n) * 256 + wave * 8;
    }

    // ---- A source (QKV: reg-staged pack; proj: gload_lds, plane=wave)
    const int r0 = m0 + sr;
    const float* apq = Af + (size_t)r0 * 256 + sc * 8;     // QKV
    const u16* apj;                                        // proj
    if constexpr (!QKV) {
        int row = m0 + (lane ^ (wave << 2));
        unsigned bA = (unsigned)row / 200u;
        apj = Ab + (size_t)bA * 51200 + (row - bA * 200) * 16
                 + (wave >> 1) * 3200 + (wave & 1) * 8;
    }

    // ---- prologue: stage tile 0 into buf 0
    if constexpr (QKV) {
        float4 f0 = *(const float4*)(apq), f1 = *(const float4*)(apq + 4);
        uint4 va = { pack2bf(f0.x, f0.y), pack2bf(f0.z, f0.w),
                     pack2bf(f1.x, f1.y), pack2bf(f1.z, f1.w) };
        *(uint4*)&a_s[0][sc][sr ^ (sc << 2)][0] = va;
    } else {
        gload16(apj, &a_s[0][wave][0][0]);
    }
#pragma unroll
    for (int p4 = 0; p4 < 4; p4++)
        gload16(bp[p4], &b_s[0][wave][p4 * 64][0]);
    __syncthreads();

#pragma unroll
    for (int t = 0; t < 8; t++) {
        const int cur = t & 1, nxt = cur ^ 1;
        const int kn = (t + 1) * 32;

        // ---- issue next-tile loads early (hide under MFMA phase)
        float4 f0, f1;
        if (t < 7) {
            if constexpr (QKV) {
                f0 = *(const float4*)(apq + kn);
                f1 = *(const float4*)(apq + kn + 4);
            } else {
                gload16(apj + (kn >> 4) * 3200, &a_s[nxt][wave][0][0]);
            }
#pragma unroll
            for (int p4 = 0; p4 < 4; p4++)
                gload16(bp[p4] + kn, &b_s[nxt][wave][p4 * 64][0]);
        }

        // ---- compute current tile
        bfrag af[4];
#pragma unroll
        for (int mi = 0; mi < 4; mi++) {
            int m = mi * 16 + l16;
            af[mi] = *(const bfrag*)&a_s[cur][quad][m ^ (quad << 2)][0];
        }
#pragma unroll
        for (int ni = 0; ni < 4; ni++) {
            int n = wave * 64 + ni * 16 + l16;
            bfrag bv = *(const bfrag*)&b_s[cur][quad][n ^ (quad << 2)][0];
#pragma unroll
            for (int mi = 0; mi < 4; mi++)
                acc[mi][ni] = mfma16(af[mi], bv, acc[mi][ni]);
        }

        // ---- write-late: A pack lands after the compute phase
        if (t < 7) {
            if constexpr (QKV) {
                uint4 va = { pack2bf(f0.x, f0.y), pack2bf(f0.z, f0.w),
                             pack2bf(f1.x, f1.y), pack2bf(f1.z, f1.w) };
                *(uint4*)&a_s[nxt][sc][sr ^ (sc << 2)][0] = va;
            }
        }
        __syncthreads();   // drains vmcnt(0)+lgkmcnt(0): buf[nxt] complete
    }

    if constexpr (QKV) {
        const float* bias = (matid == 0) ? b0 : (matid == 1) ? b1 : b2;
        u16* dst = (matid == 0) ? o0 : (matid == 1) ? o1 : o2;
#pragma unroll
        for (int ni = 0; ni < 4; ni++) {
            int nloc = wave * 64 + ni * 16 + l16;        // 0..255 within D
            float bb = bias[nloc];
            size_t hbase = (size_t)(nloc >> 4) * 3200 + (nloc & 15);
#pragma unroll
            for (int mi = 0; mi < 4; mi++) {
                int rowb = m0 + mi * 16 + quad * 4;
#pragma unroll
                for (int r = 0; r < 4; r++) {
                    unsigned row = rowb + r;
                    unsigned bb_ = row / 200u, ll = row - bb_ * 200u;
                    dst[(size_t)bb_ * 51200 + hbase + ll * 16] = f2bf(acc[mi][ni][r] + bb);
                }
            }
        }
    } else {
#pragma unroll
        for (int ni = 0; ni < 4; ni++) {
            int col = wave * 64 + ni * 16 + l16;
            float bb = b0[col];
#pragma unroll
            for (int mi = 0; mi < 4; mi++) {
                int rowb = m0 + mi * 16 + quad * 4;
#pragma unroll
                for (int r = 0; r < 4; r++)
                    o0[(size_t)(rowb + r) * 256 + col] = f2bf(acc[mi][ni][r] + bb);
            }
        }
    }
}

// ---------------------------------------------------------------------------
// MHA per (b,h), KEY-COMPACTED. grid 4096, block 256 (4 waves).
// ~50% of keys are masked; reference gives them exp(-10000+s) == 0.0 exactly
// (f32 underflow), so excluding them is numerically EXACT. Ballot-compact the
// active key indices, gather K and V^T into LDS, loop nt=ceil(cnt/16) tiles
// (typ. 7) instead of 13. S^T = K_c·Q^T keeps P in PV's A-operand layout.
// Normalization applied BEFORE the P bf16 pack (r6 numeric recipe).
// All-masked row -> identity map (== reference's uniform softmax).
// ---------------------------------------------------------------------------
__global__ __launch_bounds__(256) void attn_k(
    u16* __restrict__ Q, const u16* __restrict__ K,
    const u16* __restrict__ V, const int* __restrict__ msk)
{
    const int blk = blockIdx.x;            // b*16+h
    const int b = blk >> 4;
    const int tid = threadIdx.x;
    const int wave = tid >> 6, lane = tid & 63;
    const int quad = lane >> 4, l16 = lane & 15;
    const size_t sbase = (size_t)blk * 3200;

    const float SL2E = 0.36067376022224085f;   // 0.25 * log2(e)

    __shared__ __align__(8)  u16 kc_s[208][20];   // compacted K rows (cols 0..15 used)
    __shared__ __align__(16) u16 vt_s[16][228];   // compacted V^T [dh][i]
    __shared__ __align__(16) float am_s[224];     // pad mask: 0 if i<cnt else -1e30
    __shared__ u16 idx_s[208];
    __shared__ int wcnt_s[4];

    // ---- ballot + zero-fill
    int m = 0;
    if (tid < 200) m = (msk[b * 200 + tid] != 0) ? 1 : 0;
    u64 bal = __ballot(m);
    if (lane == 0) wcnt_s[wave] = __popcll(bal);
    if (tid < 208) {
        u64* z = (u64*)&kc_s[tid][0];
        z[0] = 0; z[1] = 0; z[2] = 0; z[3] = 0;
    }
    u32* vz = (u32*)&vt_s[0][0];
    for (int i = tid; i < 1824; i += 256) vz[i] = 0;
    __syncthreads();

    int cnt = wcnt_s[0] + wcnt_s[1] + wcnt_s[2] + wcnt_s[3];
    if (cnt == 0) {                       // all masked -> uniform (== reference)
        if (tid < 200) idx_s[tid] = (u16)tid;
        cnt = 200;
    } else if (m) {
        int woff = (wave > 0 ? wcnt_s[0] : 0) + (wave > 1 ? wcnt_s[1] : 0)
                 + (wave > 2 ? wcnt_s[2] : 0);
        idx_s[woff + __popcll(bal & ((1ull << lane) - 1ull))] = (u16)tid;
    }
    for (int i = tid; i < 224; i += 256)
        am_s[i] = (i < cnt) ? 0.f : -1e30f;
    __syncthreads();

    // ---- gather compacted K rows and V^T columns
    if (tid < cnt) {
        int row = idx_s[tid];
        const u64* ks = (const u64*)(K + sbase + row * 16);
        u64* kd = (u64*)&kc_s[tid][0];
        kd[0] = ks[0]; kd[1] = ks[1]; kd[2] = ks[2]; kd[3] = ks[3];
        const u16* vp = V + sbase + row * 16;
        bfrag v0 = *(const bfrag*)vp;
        bfrag v1 = *(const bfrag*)(vp + 8);
#pragma unroll
        for (int j = 0; j < 8; j++) {
            vt_s[j][tid]     = (u16)v0[j];
            vt_s[8 + j][tid] = (u16)v1[j];
        }
    }
    __syncthreads();

    const int nt = (cnt + 15) >> 4;        // 1..13 active key tiles

    for (int t = wave; t < 13; t += 4) {
        int lq = t * 16 + l16; if (lq > 199) lq = 199;  // clamp (writes guarded)
        sfrag qf = *(const sfrag*)(Q + sbase + lq * 16 + quad * 4);

        // ---- S^T tiles over compacted keys (exp2 domain)
        float s[13][4];
#pragma unroll
        for (int kt = 0; kt < 13; kt++) {
            if (kt < nt) {
                sfrag kf = *(const sfrag*)&kc_s[kt * 16 + l16][quad * 4];
                ffrag c = {0.f, 0.f, 0.f, 0.f};
                c = mfma16k16(kf, qf, c);
                ffrag am4 = *(const ffrag*)&am_s[kt * 16 + quad * 4];
#pragma unroll
                for (int r = 0; r < 4; r++)
                    s[kt][r] = __builtin_fmaf(c[r], SL2E, am4[r]);
            }
        }
        // ---- max: per-lane, then cross-quad (xor 16,32 joins same-q lanes)
        float mx = -3e38f;
#pragma unroll
        for (int kt = 0; kt < 13; kt++)
            if (kt < nt)
#pragma unroll
                for (int r = 0; r < 4; r++) mx = fmaxf(mx, s[kt][r]);
        mx = fmaxf(mx, __shfl_xor(mx, 16, 64));
        mx = fmaxf(mx, __shfl_xor(mx, 32, 64));
        // ---- exp2 + sum (p stored back into s)
        float sm = 0.f;
#pragma unroll
        for (int kt = 0; kt < 13; kt++) {
            if (kt < nt) {
                float p0 = __builtin_amdgcn_exp2f(s[kt][0] - mx);
                float p1 = __builtin_amdgcn_exp2f(s[kt][1] - mx);
                float p2 = __builtin_amdgcn_exp2f(s[kt][2] - mx);
                float p3 = __builtin_amdgcn_exp2f(s[kt][3] - mx);
                sm += (p0 + p1) + (p2 + p3);
                s[kt][0] = p0; s[kt][1] = p1; s[kt][2] = p2; s[kt][3] = p3;
            }
        }
        sm += __shfl_xor(sm, 16, 64);
        sm += __shfl_xor(sm, 32, 64);
        float rs = 1.0f / sm;
        // ---- normalize -> pack -> PV (fused per tile)
        ffrag o = {0.f, 0.f, 0.f, 0.f};
#pragma unroll
        for (int kt = 0; kt < 13; kt++) {
            if (kt < nt) {
                union { sfrag v; u32 u[2]; } pk;
                pk.u[0] = pack2bf(s[kt][0] * rs, s[kt][1] * rs);
                pk.u[1] = pack2bf(s[kt][2] * rs, s[kt][3] * rs);
                sfrag bv = *(const sfrag*)&vt_s[l16][kt * 16 + quad * 4];
                o = mfma16k16(pk.v, bv, o);
            }
        }
        // D row=quad*4+r = q-local, col=l16 = dh
        int lb = t * 16 + quad * 4;
        u16* qo = Q + sbase + lb * 16 + l16;
#pragma unroll
        for (int r = 0; r < 4; r++) {
            if (lb + r < 200)
                qo[r * 16] = f2bf(o[r]);   // ctx in-place over Q
        }
    }
}

// ---------------------------------------------------------------------------
// Query pooling per batch. grid 256, block 512 (8 waves). f32 out.
// Both phases: wave-per-row, 8B coalesced loads (vs 2B serial loop before).
// ---------------------------------------------------------------------------
__global__ __launch_bounds__(512) void pool_k(
    const u16* __restrict__ NO, const int* __restrict__ msk,
    const float* __restrict__ qn, float* __restrict__ out)
{
    const int b = blockIdx.x;
    const int tid = threadIdx.x;
    const int wave = tid >> 6, lane = tid & 63;

    __shared__ float q_sh[256];
    __shared__ float s_sh[200];
    __shared__ float p_sh[200];
    __shared__ float red_s[16];          // [0..7] max, [8..15] sum
    __shared__ float part_s[8][256];

    if (tid < 256) q_sh[tid] = qn[tid];
    __syncthreads();

    const u16* base = NO + (size_t)b * 51200;

    // phase 1: s_l = dot(NO[l], q) / 16 — wave w owns rows 25w..25w+24
    for (int rr = 0; rr < 25; rr++) {
        int l = wave * 25 + rr;
        u64 v = *(const u64*)(base + l * 256 + lane * 4);
        float d = bf2f((u16)v)         * q_sh[lane * 4 + 0]
                + bf2f((u16)(v >> 16)) * q_sh[lane * 4 + 1]
                + bf2f((u16)(v >> 32)) * q_sh[lane * 4 + 2]
                + bf2f((u16)(v >> 48)) * q_sh[lane * 4 + 3];
#pragma unroll
        for (int dd = 1; dd < 64; dd <<= 1) d += __shfl_xor(d, dd, 64);
        if (lane == 0) s_sh[l] = d * 0.0625f;
    }
    __syncthreads();

    // softmax over 200 (masked -> -1e9, matches reference where())
    float s = -1e30f;
    if (tid < 200) s = msk[b * 200 + tid] ? s_sh[tid] : -1e9f;
    float mw = s;
#pragma unroll
    for (int dd = 1; dd < 64; dd <<= 1) mw = fmaxf(mw, __shfl_xor(mw, dd, 64));
    if (lane == 0) red_s[wave] = mw;
    __syncthreads();
    float mmax = red_s[0];
#pragma unroll
    for (int w = 1; w < 8; w++) mmax = fmaxf(mmax, red_s[w]);
    float e = (tid < 200) ? __expf(s - mmax) : 0.f;
    float sw = e;
#pragma unroll
    for (int dd = 1; dd < 64; dd <<= 1) sw += __shfl_xor(sw, dd, 64);
    if (lane == 0) red_s[8 + wave] = sw;
    __syncthreads();
    float ssum = 0.f;
#pragma unroll
    for (int w = 0; w < 8; w++) ssum += red_s[8 + w];
    if (tid < 200) p_sh[tid] = e / ssum;
    __syncthreads();

    // phase 2: out[d] = sum_l p_l * NO[l][d] — wave-per-25-rows, lane owns 4 d
    float a0 = 0.f, a1 = 0.f, a2 = 0.f, a3 = 0.f;
    for (int rr = 0; rr < 25; rr++) {
        int l = wave * 25 + rr;
        float p = p_sh[l];
        u64 v = *(const u64*)(base + l * 256 + lane * 4);
        a0 += p * bf2f((u16)v);
        a1 += p * bf2f((u16)(v >> 16));
        a2 += p * bf2f((u16)(v >> 32));
        a3 += p * bf2f((u16)(v >> 48));
    }
    part_s[wave][lane * 4 + 0] = a0;
    part_s[wave][lane * 4 + 1] = a1;
    part_s[wave][lane * 4 + 2] = a2;
    part_s[wave][lane * 4 + 3] = a3;
    __syncthreads();
    if (tid < 256) {
        float t = 0.f;
#pragma unroll
        for (int w = 0; w < 8; w++) t += part_s[w][tid];
        out[(size_t)b * 256 + tid] = t;
    }
}

// ---------------------------------------------------------------------------
extern "C" void kernel_launch(void* const* d_in, const int* in_sizes, int n_in,
                              void* d_out, int out_size, void* d_ws, size_t ws_size,
                              hipStream_t stream) {
    const float* X   = (const float*)d_in[0];
    const int*   msk = (const int*)d_in[1];
    const float* Wq  = (const float*)d_in[2];
    const float* bq  = (const float*)d_in[3];
    const float* Wk  = (const float*)d_in[4];
    const float* bk  = (const float*)d_in[5];
    const float* Wv  = (const float*)d_in[6];
    const float* bv  = (const float*)d_in[7];
    const float* Wo  = (const float*)d_in[8];
    const float* bo  = (const float*)d_in[9];
    const float* qn  = (const float*)d_in[10];
    float* out = (float*)d_out;

    // ws layout (79,167,488 B):
    //   qbuf: Q head-major -> ctx in-place     26,214,400
    //   kbuf: K head-major -> news_out l-major 26,214,400
    //   vbuf: V head-major                     26,214,400
    //   wt:   [1024][256] bf16 weights^T          524,288
    char* ws = (char*)d_ws;
    u16* qbuf = (u16*)(ws);
    u16* kbuf = (u16*)(ws + 26214400);
    u16* vbuf = (u16*)(ws + 52428800);
    u16* wt   = (u16*)(ws + 78643200);

    wtrans_k<<<dim3(4, 4, 4), 256, 0, stream>>>(Wq, Wk, Wv, Wo, wt);

    gemm_k<true><<<dim3(800, 3), 256, 0, stream>>>(
        X, wt, bq, bk, bv, qbuf, kbuf, vbuf);

    attn_k<<<4096, 256, 0, stream>>>(qbuf, kbuf, vbuf, msk);

    gemm_k<false><<<dim3(800, 1), 256, 0, stream>>>(
        qbuf, wt + 196608, bo, nullptr, nullptr, kbuf, nullptr, nullptr);

    pool_k<<<256, 512, 0, stream>>>(kbuf, msk, qn, out);
}

// Round 3
// 237.374 us; speedup vs baseline: 1.0444x; 1.0444x over previous
//
#include <hip/hip_runtime.h>

typedef unsigned short u16;
typedef unsigned int u32;
typedef unsigned long long u64;
typedef __attribute__((ext_vector_type(8))) short bfrag;  // 8 bf16 (4 VGPRs)
typedef __attribute__((ext_vector_type(4))) short sfrag;  // 4 bf16 (2 VGPRs)
typedef __attribute__((ext_vector_type(4))) float ffrag;  // 4 fp32

// B=256, L=200, D=256, H=16, Dh=16, M=51200
// Head-major slice: [B,H,L,16], slice stride 3200 u16, b-stride 51200 u16.

__device__ __forceinline__ float bf2f(u16 u) {
    union { float f; u32 i; } c; c.i = ((u32)u) << 16; return c.f;
}
__device__ __forceinline__ u16 f2bf(float f) {           // RNE
    union { float f; u32 i; } c; c.f = f;
    u32 r = c.i + 0x7FFFu + ((c.i >> 16) & 1u);
    return (u16)(r >> 16);
}
__device__ __forceinline__ u32 pack2bf(float lo, float hi) {  // RNE pair
    union { float f; u32 i; } a, b; a.f = lo; b.f = hi;
    u32 ra = a.i + 0x7FFFu + ((a.i >> 16) & 1u);
    u32 rb = b.i + 0x7FFFu + ((b.i >> 16) & 1u);
    return (ra >> 16) | (rb & 0xFFFF0000u);
}
__device__ __forceinline__ ffrag mfma16(bfrag a, bfrag b, ffrag c) {
    return __builtin_amdgcn_mfma_f32_16x16x32_bf16(a, b, c, 0, 0, 0);
}
__device__ __forceinline__ ffrag mfma16k16(sfrag a, sfrag b, ffrag c) {
    return __builtin_amdgcn_mfma_f32_16x16x16bf16_1k(a, b, c, 0, 0, 0);
}
// Async global->LDS, 16B per lane. LDS dest = wave-uniform base + lane*16.
__device__ __forceinline__ void gload16(const u16* g, u16* l) {
    __builtin_amdgcn_global_load_lds(
        (const __attribute__((address_space(1))) u32*)g,
        (__attribute__((address_space(3))) u32*)l, 16, 0, 0);
}

// ---------------------------------------------------------------------------
// LDS-tiled transpose+cast: W[k][n] f32 -> Wt[n][k] bf16, 4 matrices.
// ---------------------------------------------------------------------------
__global__ __launch_bounds__(256) void wtrans_k(
    const float* __restrict__ W0, const float* __restrict__ W1,
    const float* __restrict__ W2, const float* __restrict__ W3,
    u16* __restrict__ Wt)
{
    __shared__ u16 t_s[64][72];
    const int mat = blockIdx.z;
    const float* W = (mat == 0) ? W0 : (mat == 1) ? W1 : (mat == 2) ? W2 : W3;
    const int k0 = blockIdx.x * 64, n0 = blockIdx.y * 64;
    const int r = threadIdx.x >> 2, cq = threadIdx.x & 3;

    const float* src = W + (size_t)(k0 + r) * 256 + n0 + cq * 16;
#pragma unroll
    for (int j = 0; j < 16; j += 4) {
        float4 f = *(const float4*)(src + j);
        t_s[cq * 16 + j + 0][r] = f2bf(f.x);
        t_s[cq * 16 + j + 1][r] = f2bf(f.y);
        t_s[cq * 16 + j + 2][r] = f2bf(f.z);
        t_s[cq * 16 + j + 3][r] = f2bf(f.w);
    }
    __syncthreads();
    u16* dst = Wt + ((size_t)mat * 256 + n0 + r) * 256 + k0 + cq * 16;
    *(bfrag*)(dst)     = *(const bfrag*)&t_s[r][cq * 16];
    *(bfrag*)(dst + 8) = *(const bfrag*)&t_s[r][cq * 16 + 8];
}

// ---------------------------------------------------------------------------
// GEMM v4: round-1 geometry (block 128x256, wave tile 64x128, acc[4][8],
// BK=32, grid (400,nmat)) + counted-vmcnt software pipeline (T3/T4):
//   - LDS triple-buffered (72 KB), prefetch distance 2.
//   - B staged with global_load_lds width=16 (4/wave into its own plane);
//     XOR swizzle applied to the per-lane GLOBAL row, LDS dest linear.
//   - QKV A: f32 loads issued at iter top (distance 2), RNE-packed and
//     ds_written AFTER the MFMA phase (write-late, T14).
//   - raw s_barrier with s_waitcnt vmcnt(4|6) — this iteration's prefetch
//     stays in flight across the barrier; never drains to 0 in steady state.
//   - proj A: pure global_load_lds (bf16 head-major ctx), distance 2.
// ---------------------------------------------------------------------------
template<bool QKV>
__global__ __launch_bounds__(256, 2) void gemm_k(
    const void* __restrict__ Avp, const u16* __restrict__ Wtp,
    const float* __restrict__ b0, const float* __restrict__ b1,
    const float* __restrict__ b2,
    u16* __restrict__ o0, u16* __restrict__ o1, u16* __restrict__ o2)
{
    const int m0 = blockIdx.x * 128;
    const int matid = blockIdx.y;          // QKV: 0=Q 1=K 2=V; proj: 0
    const int tid = threadIdx.x;
    const int wave = tid >> 6, lane = tid & 63;
    const int quad = lane >> 4, l16 = lane & 15;
    const int wm = wave >> 1, wn = wave & 1;

    __shared__ __align__(16) u16 a_s[3][4][128][8];   // 24 KB
    __shared__ __align__(16) u16 b_s[3][4][256][8];   // 48 KB

    ffrag zf = {0.f, 0.f, 0.f, 0.f};
    ffrag acc[4][8];
#pragma unroll
    for (int mi = 0; mi < 4; mi++)
#pragma unroll
        for (int ni = 0; ni < 8; ni++) acc[mi][ni] = zf;

    const int sr = tid >> 2;               // 0..63
    const int sc = tid & 3;                // 0..3 (k-octet)
    const float* Af = (const float*)Avp;
    const u16*   Ab = (const u16*)Avp;

    // ---- B gload sources: wave stages plane 'wave'; slot row x holds W row
    // (x ^ (wave<<2)), k-octet 'wave'. Lane l covers slot j*64+l.
    const u16* wb = Wtp + (size_t)matid * 65536 + wave * 8;
    u32 bofs[4];
#pragma unroll
    for (int j = 0; j < 4; j++)
        bofs[j] = (u32)(((j * 64 + lane) ^ (wave << 2)) * 256);

    // ---- QKV A sources (rows r0, r0+64, k-octet sc)
    const int r0 = m0 + sr, r1 = r0 + 64;
    const float* apq0 = Af + (size_t)r0 * 256 + sc * 8;
    const float* apq1 = Af + (size_t)r1 * 256 + sc * 8;

    // ---- proj A gload sources: wave stages plane 'wave' (k-octet wave),
    // slot row x holds ctx row m0 + (x ^ (wave<<2)).
    const u16* asrc0 = nullptr; const u16* asrc1 = nullptr;
    if constexpr (!QKV) {
        int arow0 = m0 + ((     lane) ^ (wave << 2));
        int arow1 = m0 + ((64 + lane) ^ (wave << 2));
        unsigned bA0 = (unsigned)arow0 / 200u, bA1 = (unsigned)arow1 / 200u;
        asrc0 = Ab + (size_t)bA0 * 51200 + (arow0 - bA0 * 200) * 16
                   + (wave >> 1) * 3200 + (wave & 1) * 8;
        asrc1 = Ab + (size_t)bA1 * 51200 + (arow1 - bA1 * 200) * 16
                   + (wave >> 1) * 3200 + (wave & 1) * 8;
    }

    // ---- prologue: stage tiles 0 and 1 completely, full drain once.
#pragma unroll
    for (int pt = 0; pt < 2; pt++) {
        const int kk = pt * 32;
        if constexpr (QKV) {
            float4 f0 = *(const float4*)(apq0 + kk), f1 = *(const float4*)(apq0 + kk + 4);
            float4 g0 = *(const float4*)(apq1 + kk), g1 = *(const float4*)(apq1 + kk + 4);
            uint4 va = { pack2bf(f0.x, f0.y), pack2bf(f0.z, f0.w),
                         pack2bf(f1.x, f1.y), pack2bf(f1.z, f1.w) };
            uint4 vb = { pack2bf(g0.x, g0.y), pack2bf(g0.z, g0.w),
                         pack2bf(g1.x, g1.y), pack2bf(g1.z, g1.w) };
            *(uint4*)&a_s[pt][sc][sr        ^ (sc << 2)][0] = va;
            *(uint4*)&a_s[pt][sc][(sr + 64) ^ (sc << 2)][0] = vb;
        } else {
            gload16(asrc0 + (kk >> 4) * 3200, &a_s[pt][wave][0][0]);
            gload16(asrc1 + (kk >> 4) * 3200, &a_s[pt][wave][64][0]);
        }
#pragma unroll
        for (int j = 0; j < 4; j++)
            gload16(wb + bofs[j] + kk, &b_s[pt][wave][j * 64][0]);
    }
    asm volatile("s_waitcnt vmcnt(0) lgkmcnt(0)" ::: "memory");
    __builtin_amdgcn_s_barrier();

#pragma unroll
    for (int t = 0; t < 8; t++) {
        const int cur = t % 3, nb = (t + 2) % 3;
        const int kn = (t + 2) * 32;

        // ---- issue prefetch for tile t+2 (lands across >=2 barriers)
        float4 f0, f1, g0, g1;
        if (t < 6) {
            if constexpr (QKV) {
                f0 = *(const float4*)(apq0 + kn); f1 = *(const float4*)(apq0 + kn + 4);
                g0 = *(const float4*)(apq1 + kn); g1 = *(const float4*)(apq1 + kn + 4);
            } else {
                gload16(asrc0 + (kn >> 4) * 3200, &a_s[nb][wave][0][0]);
                gload16(asrc1 + (kn >> 4) * 3200, &a_s[nb][wave][64][0]);
            }
#pragma unroll
            for (int j = 0; j < 4; j++)
                gload16(wb + bofs[j] + kn, &b_s[nb][wave][j * 64][0]);
        }

        // ---- compute tile t
        bfrag af[4];
#pragma unroll
        for (int mi = 0; mi < 4; mi++) {
            int m = wm * 64 + mi * 16 + l16;
            af[mi] = *(const bfrag*)&a_s[cur][quad][m ^ (quad << 2)][0];
        }
#pragma unroll
        for (int ni = 0; ni < 8; ni++) {
            int n = wn * 128 + ni * 16 + l16;
            bfrag bv = *(const bfrag*)&b_s[cur][quad][n ^ (quad << 2)][0];
#pragma unroll
            for (int mi = 0; mi < 4; mi++)
                acc[mi][ni] = mfma16(af[mi], bv, acc[mi][ni]);
        }

        // ---- write-late: A(t+2) pack lands after the MFMA phase
        if constexpr (QKV) {
            if (t < 6) {
                uint4 va = { pack2bf(f0.x, f0.y), pack2bf(f0.z, f0.w),
                             pack2bf(f1.x, f1.y), pack2bf(f1.z, f1.w) };
                uint4 vb = { pack2bf(g0.x, g0.y), pack2bf(g0.z, g0.w),
                             pack2bf(g1.x, g1.y), pack2bf(g1.z, g1.w) };
                *(uint4*)&a_s[nb][sc][sr        ^ (sc << 2)][0] = va;
                *(uint4*)&a_s[nb][sc][(sr + 64) ^ (sc << 2)][0] = vb;
            }
        }

        // ---- counted wait: tile t+1's loads (issued at t-1) are forced
        // complete by in-order vmcnt; this iter's prefetch stays in flight.
        if (t < 7) {
            if (t < 6) {
                if constexpr (QKV)
                    asm volatile("s_waitcnt vmcnt(4) lgkmcnt(0)" ::: "memory");
                else
                    asm volatile("s_waitcnt vmcnt(6) lgkmcnt(0)" ::: "memory");
            } else {
                asm volatile("s_waitcnt vmcnt(0) lgkmcnt(0)" ::: "memory");
            }
            __builtin_amdgcn_s_barrier();
        }
    }

    if constexpr (QKV) {
        const float* bias = (matid == 0) ? b0 : (matid == 1) ? b1 : b2;
        u16* dst = (matid == 0) ? o0 : (matid == 1) ? o1 : o2;
#pragma unroll
        for (int ni = 0; ni < 8; ni++) {
            int nloc = wn * 128 + ni * 16 + l16;         // 0..255 within D
            float bb = bias[nloc];
            size_t hbase = (size_t)(nloc >> 4) * 3200 + (nloc & 15);
#pragma unroll
            for (int mi = 0; mi < 4; mi++) {
                int rowb = m0 + wm * 64 + mi * 16 + quad * 4;
#pragma unroll
                for (int r = 0; r < 4; r++) {
                    unsigned row = rowb + r;
                    unsigned bb_ = row / 200u, ll = row - bb_ * 200u;
                    dst[(size_t)bb_ * 51200 + hbase + ll * 16] = f2bf(acc[mi][ni][r] + bb);
                }
            }
        }
    } else {
#pragma unroll
        for (int ni = 0; ni < 8; ni++) {
            int col = wn * 128 + ni * 16 + l16;
            float bb = b0[col];
#pragma unroll
            for (int mi = 0; mi < 4; mi++) {
                int rowb = m0 + wm * 64 + mi * 16 + quad * 4;
#pragma unroll
                for (int r = 0; r < 4; r++)
                    o0[(size_t)(rowb + r) * 256 + col] = f2bf(acc[mi][ni][r] + bb);
            }
        }
    }
}

// ---------------------------------------------------------------------------
// MHA per (b,h), KEY-COMPACTED. grid 4096, block 256 (4 waves).
// ~50% of keys are masked; reference gives them exp(-10000+s) == 0.0 exactly
// (f32 underflow), so excluding them is numerically EXACT. Ballot-compact the
// active key indices, gather K and V^T into LDS, loop nt=ceil(cnt/16) tiles
// (typ. 7) instead of 13. S^T = K_c·Q^T keeps P in PV's A-operand layout.
// Normalization applied BEFORE the P bf16 pack (r6 numeric recipe).
// All-masked row -> identity map (== reference's uniform softmax).
// ---------------------------------------------------------------------------
__global__ __launch_bounds__(256) void attn_k(
    u16* __restrict__ Q, const u16* __restrict__ K,
    const u16* __restrict__ V, const int* __restrict__ msk)
{
    const int blk = blockIdx.x;            // b*16+h
    const int b = blk >> 4;
    const int tid = threadIdx.x;
    const int wave = tid >> 6, lane = tid & 63;
    const int quad = lane >> 4, l16 = lane & 15;
    const size_t sbase = (size_t)blk * 3200;

    const float SL2E = 0.36067376022224085f;   // 0.25 * log2(e)

    __shared__ __align__(8)  u16 kc_s[208][20];   // compacted K rows (cols 0..15 used)
    __shared__ __align__(16) u16 vt_s[16][228];   // compacted V^T [dh][i]
    __shared__ __align__(16) float am_s[224];     // pad mask: 0 if i<cnt else -1e30
    __shared__ u16 idx_s[208];
    __shared__ int wcnt_s[4];

    // ---- ballot + zero-fill
    int m = 0;
    if (tid < 200) m = (msk[b * 200 + tid] != 0) ? 1 : 0;
    u64 bal = __ballot(m);
    if (lane == 0) wcnt_s[wave] = __popcll(bal);
    if (tid < 208) {
        u64* z = (u64*)&kc_s[tid][0];
        z[0] = 0; z[1] = 0; z[2] = 0; z[3] = 0;
    }
    u32* vz = (u32*)&vt_s[0][0];
    for (int i = tid; i < 1824; i += 256) vz[i] = 0;
    __syncthreads();

    int cnt = wcnt_s[0] + wcnt_s[1] + wcnt_s[2] + wcnt_s[3];
    if (cnt == 0) {                       // all masked -> uniform (== reference)
        if (tid < 200) idx_s[tid] = (u16)tid;
        cnt = 200;
    } else if (m) {
        int woff = (wave > 0 ? wcnt_s[0] : 0) + (wave > 1 ? wcnt_s[1] : 0)
                 + (wave > 2 ? wcnt_s[2] : 0);
        idx_s[woff + __popcll(bal & ((1ull << lane) - 1ull))] = (u16)tid;
    }
    for (int i = tid; i < 224; i += 256)
        am_s[i] = (i < cnt) ? 0.f : -1e30f;
    __syncthreads();

    // ---- gather compacted K rows and V^T columns
    if (tid < cnt) {
        int row = idx_s[tid];
        const u64* ks = (const u64*)(K + sbase + row * 16);
        u64* kd = (u64*)&kc_s[tid][0];
        kd[0] = ks[0]; kd[1] = ks[1]; kd[2] = ks[2]; kd[3] = ks[3];
        const u16* vp = V + sbase + row * 16;
        bfrag v0 = *(const bfrag*)vp;
        bfrag v1 = *(const bfrag*)(vp + 8);
#pragma unroll
        for (int j = 0; j < 8; j++) {
            vt_s[j][tid]     = (u16)v0[j];
            vt_s[8 + j][tid] = (u16)v1[j];
        }
    }
    __syncthreads();

    const int nt = (cnt + 15) >> 4;        // 1..13 active key tiles

    for (int t = wave; t < 13; t += 4) {
        int lq = t * 16 + l16; if (lq > 199) lq = 199;  // clamp (writes guarded)
        sfrag qf = *(const sfrag*)(Q + sbase + lq * 16 + quad * 4);

        // ---- S^T tiles over compacted keys (exp2 domain)
        float s[13][4];
#pragma unroll
        for (int kt = 0; kt < 13; kt++) {
            if (kt < nt) {
                sfrag kf = *(const sfrag*)&kc_s[kt * 16 + l16][quad * 4];
                ffrag c = {0.f, 0.f, 0.f, 0.f};
                c = mfma16k16(kf, qf, c);
                ffrag am4 = *(const ffrag*)&am_s[kt * 16 + quad * 4];
#pragma unroll
                for (int r = 0; r < 4; r++)
                    s[kt][r] = __builtin_fmaf(c[r], SL2E, am4[r]);
            }
        }
        // ---- max: per-lane, then cross-quad (xor 16,32 joins same-q lanes)
        float mx = -3e38f;
#pragma unroll
        for (int kt = 0; kt < 13; kt++)
            if (kt < nt)
#pragma unroll
                for (int r = 0; r < 4; r++) mx = fmaxf(mx, s[kt][r]);
        mx = fmaxf(mx, __shfl_xor(mx, 16, 64));
        mx = fmaxf(mx, __shfl_xor(mx, 32, 64));
        // ---- exp2 + sum (p stored back into s)
        float sm = 0.f;
#pragma unroll
        for (int kt = 0; kt < 13; kt++) {
            if (kt < nt) {
                float p0 = __builtin_amdgcn_exp2f(s[kt][0] - mx);
                float p1 = __builtin_amdgcn_exp2f(s[kt][1] - mx);
                float p2 = __builtin_amdgcn_exp2f(s[kt][2] - mx);
                float p3 = __builtin_amdgcn_exp2f(s[kt][3] - mx);
                sm += (p0 + p1) + (p2 + p3);
                s[kt][0] = p0; s[kt][1] = p1; s[kt][2] = p2; s[kt][3] = p3;
            }
        }
        sm += __shfl_xor(sm, 16, 64);
        sm += __shfl_xor(sm, 32, 64);
        float rs = 1.0f / sm;
        // ---- normalize -> pack -> PV (fused per tile)
        ffrag o = {0.f, 0.f, 0.f, 0.f};
#pragma unroll
        for (int kt = 0; kt < 13; kt++) {
            if (kt < nt) {
                union { sfrag v; u32 u[2]; } pk;
                pk.u[0] = pack2bf(s[kt][0] * rs, s[kt][1] * rs);
                pk.u[1] = pack2bf(s[kt][2] * rs, s[kt][3] * rs);
                sfrag bv = *(const sfrag*)&vt_s[l16][kt * 16 + quad * 4];
                o = mfma16k16(pk.v, bv, o);
            }
        }
        // D row=quad*4+r = q-local, col=l16 = dh
        int lb = t * 16 + quad * 4;
        u16* qo = Q + sbase + lb * 16 + l16;
#pragma unroll
        for (int r = 0; r < 4; r++) {
            if (lb + r < 200)
                qo[r * 16] = f2bf(o[r]);   // ctx in-place over Q
        }
    }
}

// ---------------------------------------------------------------------------
// Query pooling per batch. grid 256, block 512 (8 waves). f32 out.
// Both phases: wave-per-row, 8B coalesced loads (vs 2B serial loop before).
// ---------------------------------------------------------------------------
__global__ __launch_bounds__(512) void pool_k(
    const u16* __restrict__ NO, const int* __restrict__ msk,
    const float* __restrict__ qn, float* __restrict__ out)
{
    const int b = blockIdx.x;
    const int tid = threadIdx.x;
    const int wave = tid >> 6, lane = tid & 63;

    __shared__ float q_sh[256];
    __shared__ float s_sh[200];
    __shared__ float p_sh[200];
    __shared__ float red_s[16];          // [0..7] max, [8..15] sum
    __shared__ float part_s[8][256];

    if (tid < 256) q_sh[tid] = qn[tid];
    __syncthreads();

    const u16* base = NO + (size_t)b * 51200;

    // phase 1: s_l = dot(NO[l], q) / 16 — wave w owns rows 25w..25w+24
    for (int rr = 0; rr < 25; rr++) {
        int l = wave * 25 + rr;
        u64 v = *(const u64*)(base + l * 256 + lane * 4);
        float d = bf2f((u16)v)         * q_sh[lane * 4 + 0]
                + bf2f((u16)(v >> 16)) * q_sh[lane * 4 + 1]
                + bf2f((u16)(v >> 32)) * q_sh[lane * 4 + 2]
                + bf2f((u16)(v >> 48)) * q_sh[lane * 4 + 3];
#pragma unroll
        for (int dd = 1; dd < 64; dd <<= 1) d += __shfl_xor(d, dd, 64);
        if (lane == 0) s_sh[l] = d * 0.0625f;
    }
    __syncthreads();

    // softmax over 200 (masked -> -1e9, matches reference where())
    float s = -1e30f;
    if (tid < 200) s = msk[b * 200 + tid] ? s_sh[tid] : -1e9f;
    float mw = s;
#pragma unroll
    for (int dd = 1; dd < 64; dd <<= 1) mw = fmaxf(mw, __shfl_xor(mw, dd, 64));
    if (lane == 0) red_s[wave] = mw;
    __syncthreads();
    float mmax = red_s[0];
#pragma unroll
    for (int w = 1; w < 8; w++) mmax = fmaxf(mmax, red_s[w]);
    float e = (tid < 200) ? __expf(s - mmax) : 0.f;
    float sw = e;
#pragma unroll
    for (int dd = 1; dd < 64; dd <<= 1) sw += __shfl_xor(sw, dd, 64);
    if (lane == 0) red_s[8 + wave] = sw;
    __syncthreads();
    float ssum = 0.f;
#pragma unroll
    for (int w = 0; w < 8; w++) ssum += red_s[8 + w];
    if (tid < 200) p_sh[tid] = e / ssum;
    __syncthreads();

    // phase 2: out[d] = sum_l p_l * NO[l][d] — wave-per-25-rows, lane owns 4 d
    float a0 = 0.f, a1 = 0.f, a2 = 0.f, a3 = 0.f;
    for (int rr = 0; rr < 25; rr++) {
        int l = wave * 25 + rr;
        float p = p_sh[l];
        u64 v = *(const u64*)(base + l * 256 + lane * 4);
        a0 += p * bf2f((u16)v);
        a1 += p * bf2f((u16)(v >> 16));
        a2 += p * bf2f((u16)(v >> 32));
        a3 += p * bf2f((u16)(v >> 48));
    }
    part_s[wave][lane * 4 + 0] = a0;
    part_s[wave][lane * 4 + 1] = a1;
    part_s[wave][lane * 4 + 2] = a2;
    part_s[wave][lane * 4 + 3] = a3;
    __syncthreads();
    if (tid < 256) {
        float t = 0.f;
#pragma unroll
        for (int w = 0; w < 8; w++) t += part_s[w][tid];
        out[(size_t)b * 256 + tid] = t;
    }
}

// ---------------------------------------------------------------------------
extern "C" void kernel_launch(void* const* d_in, const int* in_sizes, int n_in,
                              void* d_out, int out_size, void* d_ws, size_t ws_size,
                              hipStream_t stream) {
    const float* X   = (const float*)d_in[0];
    const int*   msk = (const int*)d_in[1];
    const float* Wq  = (const float*)d_in[2];
    const float* bq  = (const float*)d_in[3];
    const float* Wk  = (const float*)d_in[4];
    const float* bk  = (const float*)d_in[5];
    const float* Wv  = (const float*)d_in[6];
    const float* bv  = (const float*)d_in[7];
    const float* Wo  = (const float*)d_in[8];
    const float* bo  = (const float*)d_in[9];
    const float* qn  = (const float*)d_in[10];
    float* out = (float*)d_out;

    // ws layout (79,167,488 B):
    //   qbuf: Q head-major -> ctx in-place     26,214,400
    //   kbuf: K head-major -> news_out l-major 26,214,400
    //   vbuf: V head-major                     26,214,400
    //   wt:   [1024][256] bf16 weights^T          524,288
    char* ws = (char*)d_ws;
    u16* qbuf = (u16*)(ws);
    u16* kbuf = (u16*)(ws + 26214400);
    u16* vbuf = (u16*)(ws + 52428800);
    u16* wt   = (u16*)(ws + 78643200);

    wtrans_k<<<dim3(4, 4, 4), 256, 0, stream>>>(Wq, Wk, Wv, Wo, wt);

    gemm_k<true><<<dim3(400, 3), 256, 0, stream>>>(
        X, wt, bq, bk, bv, qbuf, kbuf, vbuf);

    attn_k<<<4096, 256, 0, stream>>>(qbuf, kbuf, vbuf, msk);

    gemm_k<false><<<dim3(400, 1), 256, 0, stream>>>(
        qbuf, wt + 196608, bo, nullptr, nullptr, kbuf, nullptr, nullptr);

    pool_k<<<256, 512, 0, stream>>>(kbuf, msk, qn, out);
}